// Round 2
// baseline (130.917 us; speedup 1.0000x reference)
//
#include <hip/hip_runtime.h>
#include <hip/hip_bf16.h>

typedef unsigned char  u8;
typedef unsigned int   u32;
typedef __attribute__((ext_vector_type(4))) int   int4v;
typedef __attribute__((ext_vector_type(8))) int   int8v;
typedef __attribute__((ext_vector_type(4))) float float4v;

#define N_ROWS 4096
#define DIM    1024
#define MARGIN 0.5f
#define FP4_SCALE 32.0f          // rows scaled to ~N(0,1) before e2m1 quantization
#define INV_SCALE2 (1.0f / (FP4_SCALE * FP4_SCALE))
#define ROWB 512                 // bytes per row in fp4 (1024 elems / 2)

#define BM 128
#define BN 128
#define NBLK ((N_ROWS / BM) * (N_ROWS / BN))   // 1024 negloss blocks

// ---------------- helpers ----------------

__device__ __forceinline__ float wave_reduce(float v) {
    #pragma unroll
    for (int off = 32; off > 0; off >>= 1) v += __shfl_xor(v, off, 64);
    return v;   // butterfly: ALL lanes hold the sum
}

// e2m1 quantization: grid {0,.5,1,1.5,2,3,4,6}, input pre-scaled to ~N(0,1).
__device__ __forceinline__ u32 q4(float v) {
    float a = fabsf(v);
    u32 c = (a >= 0.25f) + (a >= 0.75f) + (a >= 1.25f) + (a >= 1.75f)
          + (a >= 2.5f)  + (a >= 3.5f)  + (a >= 5.0f);
    return c | (v < 0.0f ? 8u : 0u);
}

// ---------------- kernel 1: norms + positive term + fp4 pre-normalized copies ----------------
// TWO waves per row (half-row each). 2048 blocks x 256 thr. Lane: 8 fp32/input
// -> 8 fp4 nibbles = 1 dword store per input. Also zero-inits the ticket used
// by negloss's fused last-block finalize (kernel boundary = visibility).

__global__ __launch_bounds__(256) void rowprep(
        const float* __restrict__ img, const float* __restrict__ txt,
        u8* __restrict__ imgn, u8* __restrict__ txtn,
        float* __restrict__ pospart, u32* __restrict__ ticket) {
    const int t = threadIdx.x;
    const int wave = t >> 6, lane = t & 63;
    const int row  = blockIdx.x * 2 + (wave >> 1);
    const int half = wave & 1;

    if (blockIdx.x == 0 && t == 0) *ticket = 0u;

    const float4* ip = (const float4*)img + (size_t)row * 256 + half * 128;
    const float4* tp = (const float4*)txt + (size_t)row * 256 + half * 128;

    float4 iv[2], tv[2];
    #pragma unroll
    for (int k = 0; k < 2; ++k) {
        iv[k] = ip[k * 64 + lane];
        tv[k] = tp[k * 64 + lane];
    }

    float sii = 0.f, si2 = 0.f, st2 = 0.f;
    #pragma unroll
    for (int k = 0; k < 2; ++k) {
        sii += iv[k].x*tv[k].x + iv[k].y*tv[k].y + iv[k].z*tv[k].z + iv[k].w*tv[k].w;
        si2 += iv[k].x*iv[k].x + iv[k].y*iv[k].y + iv[k].z*iv[k].z + iv[k].w*iv[k].w;
        st2 += tv[k].x*tv[k].x + tv[k].y*tv[k].y + tv[k].z*tv[k].z + tv[k].w*tv[k].w;
    }

    sii = wave_reduce(sii);
    si2 = wave_reduce(si2);
    st2 = wave_reduce(st2);

    __shared__ float red[4][3];
    if (lane == 0) { red[wave][0] = sii; red[wave][1] = si2; red[wave][2] = st2; }
    __syncthreads();
    const int pw = wave ^ 1;
    sii += red[pw][0];
    si2 += red[pw][1];
    st2 += red[pw][2];

    float ni = fmaxf(sqrtf(si2), 1e-8f);
    float nt = fmaxf(sqrtf(st2), 1e-8f);
    float ii = 1.0f / ni, it = 1.0f / nt;
    float si = FP4_SCALE * ii, st = FP4_SCALE * it;

    // pack 8 fp4 codes per input into one dword (elem j -> nibble j)
    u32 pa = 0, pb = 0;
    #pragma unroll
    for (int k = 0; k < 2; ++k) {
        pa |= q4(iv[k].x * si) << (k*16 + 0);  pa |= q4(iv[k].y * si) << (k*16 + 4);
        pa |= q4(iv[k].z * si) << (k*16 + 8);  pa |= q4(iv[k].w * si) << (k*16 + 12);
        pb |= q4(tv[k].x * st) << (k*16 + 0);  pb |= q4(tv[k].y * st) << (k*16 + 4);
        pb |= q4(tv[k].z * st) << (k*16 + 8);  pb |= q4(tv[k].w * st) << (k*16 + 12);
    }
    // row = 512 B = 128 dwords; half-row = 64 dwords
    ((u32*)imgn)[(size_t)row * 128 + half * 64 + lane] = pa;
    ((u32*)txtn)[(size_t)row * 128 + half * 64 + lane] = pb;

    if (half == 0 && lane == 0) {
        float d = 1.0f - sii * ii * it;
        pospart[row] = d * d;
    }
}

// ---------------- kernel 2: pairwise cosine GEMM (MX-fp4 K=128) + fused hinge ----------------
// A (imgn), B (txtn): row-major [4096][512 B] fp4 e2m1, pre-normalized * 32.
// 128x128 block tile, 4 waves (2x2), 64x64 wave tiles of 4x4 16x16x128
// scaled-MFMA (fmt=4: fp4, scales=1.0).
//
// NO-LDS VERSION (catalog common-mistake #7: don't stage L2-resident data).
// imgn+txtn = 4 MB total fp4 -> fits every XCD's 4 MB L2 (per-XCD working
// set ~2.25 MB with default dispatch). Fragments are loaded DIRECTLY from
// global per lane: per k-step each wave issues 8 x global_load_dwordx4
// forming 16 x 64 B segments (4 lanes x consecutive 16 B chunks) -> L2's
// efficient granule. Zero barriers -> compiler software-pipelines the fully
// unrolled 8 k-steps; 4 blocks/CU give TLP. Per-lane data is bit-identical
// to the proven LDS kernel (its XOR swizzle canceled between write & read).
//
// L2 read traffic: 1024 blk x 4 waves x 8 ks x 8 KB = 256 MB @ 34.5 TB/s
// ~ 7.4 us, overlapping the 4.8 us MFMA floor (34.4 GFLOP @ ~7.2 PF fp4).
//
// Fused finalize (threadfence+ticket last-block), bit-exact vs the old
// 3-kernel version — proven in round 1 (absmax 0.0).

__global__ __launch_bounds__(256) void negloss(
        const u8* __restrict__ A, const u8* __restrict__ B,
        const float* __restrict__ pospart,
        float* __restrict__ negpart, u32* __restrict__ ticket,
        float* __restrict__ out) {
    const int tid = threadIdx.x;
    const int wave = tid >> 6, lane = tid & 63;
    const int wr = wave >> 1, wc = wave & 1;
    const int rA0 = blockIdx.y * BM;
    const int rB0 = blockIdx.x * BN;

    // fragment geometry (16x16x128, fp4: 16 B/lane per matrix per k-step)
    const int mrow = lane & 15;     // fragment row within 16
    const int kg   = lane >> 4;     // K-subchunk (32 elems = 16 B) within k-step

    const u8* pA[4];
    const u8* pB[4];
    #pragma unroll
    for (int i = 0; i < 4; ++i) {
        pA[i] = A + (size_t)(rA0 + wr * 64 + i * 16 + mrow) * ROWB + kg * 16;
        pB[i] = B + (size_t)(rB0 + wc * 64 + i * 16 + mrow) * ROWB + kg * 16;
    }

    float4v acc[4][4] = {};

    #pragma unroll
    for (int ks = 0; ks < 8; ++ks) {            // K = 8 x 128 elems
        const int off = ks * 64;                // 128 K-elems = 64 B per row
        int8v af[4], bf[4];
        #pragma unroll
        for (int i = 0; i < 4; ++i) {
            int4v a = *(const int4v*)(pA[i] + off);
            int4v b = *(const int4v*)(pB[i] + off);
            af[i] = int8v{a[0], a[1], a[2], a[3], 0, 0, 0, 0};
            bf[i] = int8v{b[0], b[1], b[2], b[3], 0, 0, 0, 0};
        }
        #pragma unroll
        for (int i = 0; i < 4; ++i)
            #pragma unroll
            for (int j = 0; j < 4; ++j)
                acc[i][j] = __builtin_amdgcn_mfma_scale_f32_16x16x128_f8f6f4(
                    af[i], bf[j], acc[i][j],
                    4 /*A fmt: fp4 e2m1*/, 4 /*B fmt: fp4 e2m1*/,
                    0, 0x7F7F7F7F /*scale A = 1.0*/,
                    0, 0x7F7F7F7F /*scale B = 1.0*/);
    }

    // epilogue: C/D layout (16x16 shapes): col = lane&15, row = (lane>>4)*4 + reg
    float local = 0.0f;
    const int crow = (lane >> 4) * 4;
    const int ccol = lane & 15;
    #pragma unroll
    for (int i = 0; i < 4; ++i) {
        int gi_base = rA0 + wr * 64 + i * 16 + crow;
        #pragma unroll
        for (int j = 0; j < 4; ++j) {
            int gj = rB0 + wc * 64 + j * 16 + ccol;
            #pragma unroll
            for (int r = 0; r < 4; ++r) {
                float sim = acc[i][j][r] * INV_SCALE2;
                float h = fmaxf(sim - MARGIN, 0.0f);
                if (gi_base + r == gj) h = 0.0f;   // diagonal zeroed
                local += h * h;
            }
        }
    }

    local = wave_reduce(local);
    __shared__ float part[4];
    __shared__ int lastflag;
    if (lane == 0) part[wave] = local;
    __syncthreads();
    if (tid == 0) {
        float bsum = part[0] + part[1] + part[2] + part[3];
        int bid = blockIdx.y * gridDim.x + blockIdx.x;
        negpart[bid] = bsum;
        __threadfence();                       // release negpart (device scope)
        u32 prev = atomicAdd(ticket, 1u);      // device-scope atomic
        lastflag = (prev == NBLK - 1);
    }
    __syncthreads();
    if (!lastflag) return;

    // ---- fused finalize (last block only) — identical reduction tree to the
    // old finalize kernel, so the result is bit-exact.
    __threadfence();                           // acquire: invalidate caches
    float sp = 0.f, sn = 0.f;
    #pragma unroll
    for (int i = 0; i < 16; ++i) sp += pospart[i * 256 + tid];
    #pragma unroll
    for (int i = 0; i < 4;  ++i) sn += negpart[i * 256 + tid];
    sp = wave_reduce(sp);
    sn = wave_reduce(sn);
    __shared__ float rp[4], rn[4];
    if (lane == 0) { rp[wave] = sp; rn[wave] = sn; }
    __syncthreads();
    if (tid == 0) {
        float pos = rp[0] + rp[1] + rp[2] + rp[3];
        float neg = rn[0] + rn[1] + rn[2] + rn[3];
        out[0] = pos * (1.0f / (float)N_ROWS)
               + neg * (1.0f / ((float)N_ROWS * (float)N_ROWS));
    }
}

// ---------------- launch ----------------

extern "C" void kernel_launch(void* const* d_in, const int* in_sizes, int n_in,
                              void* d_out, int out_size, void* d_ws, size_t ws_size,
                              hipStream_t stream) {
    const float* img = (const float*)d_in[0];
    const float* txt = (const float*)d_in[1];
    float* out = (float*)d_out;

    u8* imgn = (u8*)d_ws;                                     // 2 MiB (fp4)
    u8* txtn = imgn + (size_t)N_ROWS * ROWB;                  // 2 MiB
    float* pospart = (float*)(txtn + (size_t)N_ROWS * ROWB);  // 16 KiB (4096)
    float* negpart = pospart + 4096;                          // 4 KiB (1024)
    u32* ticket = (u32*)(negpart + 1024);                     // 4 B

    rowprep<<<N_ROWS / 2, 256, 0, stream>>>(img, txt, imgn, txtn, pospart, ticket);
    negloss<<<dim3(N_ROWS / BN, N_ROWS / BM), 256, 0, stream>>>(
        imgn, txtn, pospart, negpart, ticket, out);
}

// Round 3
// 107.684 us; speedup vs baseline: 1.2158x; 1.2158x over previous
//
#include <hip/hip_runtime.h>
#include <hip/hip_bf16.h>

typedef unsigned char  u8;
typedef unsigned int   u32;
typedef __attribute__((ext_vector_type(4))) int   int4v;
typedef __attribute__((ext_vector_type(8))) int   int8v;
typedef __attribute__((ext_vector_type(4))) float float4v;

#define N_ROWS 4096
#define DIM    1024
#define MARGIN 0.5f
#define FP4_SCALE 32.0f          // rows scaled to ~N(0,1) before e2m1 quantization
#define INV_SCALE2 (1.0f / (FP4_SCALE * FP4_SCALE))
#define ROWB 512                 // bytes per row in fp4 (1024 elems / 2)

#define BM 128
#define BN 128
#define NBLK ((N_ROWS / BM) * (N_ROWS / BN))   // 1024 negloss blocks

// ---------------- helpers ----------------

__device__ __forceinline__ float wave_reduce(float v) {
    #pragma unroll
    for (int off = 32; off > 0; off >>= 1) v += __shfl_xor(v, off, 64);
    return v;   // butterfly: ALL lanes hold the sum
}

__device__ __forceinline__ void gl_lds16(const void* g, void* l) {
    __builtin_amdgcn_global_load_lds(
        (const __attribute__((address_space(1))) void*)g,
        (__attribute__((address_space(3))) void*)l,
        16, 0, 0);
}

// e2m1 quantization: grid {0,.5,1,1.5,2,3,4,6}, input pre-scaled to ~N(0,1).
__device__ __forceinline__ u32 q4(float v) {
    float a = fabsf(v);
    u32 c = (a >= 0.25f) + (a >= 0.75f) + (a >= 1.25f) + (a >= 1.75f)
          + (a >= 2.5f)  + (a >= 3.5f)  + (a >= 5.0f);
    return c | (v < 0.0f ? 8u : 0u);
}

// ---------------- kernel 1: norms + positive term + fp4 pre-normalized copies ----------------
// TWO waves per row (half-row each). 2048 blocks x 256 thr. Lane: 8 fp32/input
// -> 8 fp4 nibbles = 1 dword store per input. Also zero-inits the ticket used
// by negloss's fused last-block finalize (kernel boundary = visibility).

__global__ __launch_bounds__(256) void rowprep(
        const float* __restrict__ img, const float* __restrict__ txt,
        u8* __restrict__ imgn, u8* __restrict__ txtn,
        float* __restrict__ pospart, u32* __restrict__ ticket) {
    const int t = threadIdx.x;
    const int wave = t >> 6, lane = t & 63;
    const int row  = blockIdx.x * 2 + (wave >> 1);
    const int half = wave & 1;

    if (blockIdx.x == 0 && t == 0) *ticket = 0u;

    const float4* ip = (const float4*)img + (size_t)row * 256 + half * 128;
    const float4* tp = (const float4*)txt + (size_t)row * 256 + half * 128;

    float4 iv[2], tv[2];
    #pragma unroll
    for (int k = 0; k < 2; ++k) {
        iv[k] = ip[k * 64 + lane];
        tv[k] = tp[k * 64 + lane];
    }

    float sii = 0.f, si2 = 0.f, st2 = 0.f;
    #pragma unroll
    for (int k = 0; k < 2; ++k) {
        sii += iv[k].x*tv[k].x + iv[k].y*tv[k].y + iv[k].z*tv[k].z + iv[k].w*tv[k].w;
        si2 += iv[k].x*iv[k].x + iv[k].y*iv[k].y + iv[k].z*iv[k].z + iv[k].w*iv[k].w;
        st2 += tv[k].x*tv[k].x + tv[k].y*tv[k].y + tv[k].z*tv[k].z + tv[k].w*tv[k].w;
    }

    sii = wave_reduce(sii);
    si2 = wave_reduce(si2);
    st2 = wave_reduce(st2);

    __shared__ float red[4][3];
    if (lane == 0) { red[wave][0] = sii; red[wave][1] = si2; red[wave][2] = st2; }
    __syncthreads();
    const int pw = wave ^ 1;
    sii += red[pw][0];
    si2 += red[pw][1];
    st2 += red[pw][2];

    float ni = fmaxf(sqrtf(si2), 1e-8f);
    float nt = fmaxf(sqrtf(st2), 1e-8f);
    float ii = 1.0f / ni, it = 1.0f / nt;
    float si = FP4_SCALE * ii, st = FP4_SCALE * it;

    // pack 8 fp4 codes per input into one dword (elem j -> nibble j)
    u32 pa = 0, pb = 0;
    #pragma unroll
    for (int k = 0; k < 2; ++k) {
        pa |= q4(iv[k].x * si) << (k*16 + 0);  pa |= q4(iv[k].y * si) << (k*16 + 4);
        pa |= q4(iv[k].z * si) << (k*16 + 8);  pa |= q4(iv[k].w * si) << (k*16 + 12);
        pb |= q4(tv[k].x * st) << (k*16 + 0);  pb |= q4(tv[k].y * st) << (k*16 + 4);
        pb |= q4(tv[k].z * st) << (k*16 + 8);  pb |= q4(tv[k].w * st) << (k*16 + 12);
    }
    // row = 512 B = 128 dwords; half-row = 64 dwords
    ((u32*)imgn)[(size_t)row * 128 + half * 64 + lane] = pa;
    ((u32*)txtn)[(size_t)row * 128 + half * 64 + lane] = pb;

    if (half == 0 && lane == 0) {
        float d = 1.0f - sii * ii * it;
        pospart[row] = d * d;
    }
}

// ---------------- kernel 2: pairwise cosine GEMM (MX-fp4 K=128) + fused hinge ----------------
// A (imgn), B (txtn): row-major [4096][512 B] fp4 e2m1, pre-normalized * 32.
// REVERTED to the round-0 proven structure (best of 3 measured variants:
// r0 LDS/BK=256 ~28us < r1 dbuf/BK=128 ~50us < r2 no-LDS 59.5us latency-bound
// at MfmaUtil 5%). global_load_lds + 2-phase loop IS the latency hiding here.
// 128x128 block tile, 4 waves (2x2), 64x64 wave tiles of 4x4 16x16x128
// scaled-MFMA (fmt=4: fp4, scales=1.0). BK=256 elems = 128 B rows; XOR-16B-
// chunk swizzle; fragment = ONE b128 per matrix per k-step.
//
// PLUS the fused finalize (threadfence+ticket last-block, verified bit-exact
// in rounds 1-2: absmax 0.0) — removes the finalize launch + 1-CU tail.

__global__ __launch_bounds__(256) void negloss(
        const u8* __restrict__ A, const u8* __restrict__ B,
        const float* __restrict__ pospart,
        float* __restrict__ negpart, u32* __restrict__ ticket,
        float* __restrict__ out) {
    __shared__ __align__(16) u8 sA[BM * 128];   // 16 KiB (128 rows x 256 K-elems)
    __shared__ __align__(16) u8 sB[BN * 128];   // 16 KiB

    const int tid = threadIdx.x;
    const int wave = tid >> 6, lane = tid & 63;
    const int wr = wave >> 1, wc = wave & 1;
    const int rA0 = blockIdx.y * BM;
    const int rB0 = blockIdx.x * BN;

    const int mrow = lane & 15;     // fragment row within 16
    const int kg = lane >> 4;       // k-group: 32 K-elems = 16 B per k-step

    // staging: load r (0..3): row = r*32 + wave*8 + (lane>>3),
    // swizzled chunk lc = (lane&7)^(lane>>3) (r/iter-invariant),
    // LDS dest (wave-uniform) = r*4096 + wave*1024.
    const int lc = (lane & 7) ^ (lane >> 3);
    const u8* gA0 = A + (size_t)(rA0 + wave * 8 + (lane >> 3)) * ROWB + lc * 16;
    const u8* gB0 = B + (size_t)(rB0 + wave * 8 + (lane >> 3)) * ROWB + lc * 16;

    float4v acc[4][4] = {};

    for (int it = 0; it < 4; ++it) {            // BK = 256 elems = 128 B
        __syncthreads();            // prior iter's LDS reads done
        #pragma unroll
        for (int r = 0; r < 4; ++r) {
            int uoff = r * 4096 + wave * 1024;
            gl_lds16(gA0 + (size_t)r * (32 * ROWB) + it * 128, (char*)sA + uoff);
            gl_lds16(gB0 + (size_t)r * (32 * ROWB) + it * 128, (char*)sB + uoff);
        }
        __syncthreads();            // staging visible

        #pragma unroll
        for (int s = 0; s < 2; ++s) {           // two K=128 steps per iter
            const int ch = s * 4 + kg;          // logical 16B chunk for this k-step
            int8v af[4], bf[4];
            #pragma unroll
            for (int i = 0; i < 4; ++i) {
                int ra = wr * 64 + i * 16 + mrow;
                int4v a = *(const int4v*)(sA + ra * 128 + (ch ^ (ra & 7)) * 16);
                int rb = wc * 64 + i * 16 + mrow;
                int4v b = *(const int4v*)(sB + rb * 128 + (ch ^ (rb & 7)) * 16);
                af[i] = int8v{a[0], a[1], a[2], a[3], 0, 0, 0, 0};
                bf[i] = int8v{b[0], b[1], b[2], b[3], 0, 0, 0, 0};
            }
            #pragma unroll
            for (int i = 0; i < 4; ++i)
                #pragma unroll
                for (int j = 0; j < 4; ++j)
                    acc[i][j] = __builtin_amdgcn_mfma_scale_f32_16x16x128_f8f6f4(
                        af[i], bf[j], acc[i][j],
                        4 /*A fmt: fp4 e2m1*/, 4 /*B fmt: fp4 e2m1*/,
                        0, 0x7F7F7F7F /*scale A = 1.0*/,
                        0, 0x7F7F7F7F /*scale B = 1.0*/);
        }
    }

    // epilogue: C/D layout (16x16 shapes): col = lane&15, row = (lane>>4)*4 + reg
    float local = 0.0f;
    const int crow = (lane >> 4) * 4;
    const int ccol = lane & 15;
    #pragma unroll
    for (int i = 0; i < 4; ++i) {
        int gi_base = rA0 + wr * 64 + i * 16 + crow;
        #pragma unroll
        for (int j = 0; j < 4; ++j) {
            int gj = rB0 + wc * 64 + j * 16 + ccol;
            #pragma unroll
            for (int r = 0; r < 4; ++r) {
                float sim = acc[i][j][r] * INV_SCALE2;
                float h = fmaxf(sim - MARGIN, 0.0f);
                if (gi_base + r == gj) h = 0.0f;   // diagonal zeroed
                local += h * h;
            }
        }
    }

    local = wave_reduce(local);
    __shared__ float part[4];
    __shared__ int lastflag;
    if (lane == 0) part[wave] = local;
    __syncthreads();
    if (tid == 0) {
        float bsum = part[0] + part[1] + part[2] + part[3];
        int bid = blockIdx.y * gridDim.x + blockIdx.x;
        negpart[bid] = bsum;
        __threadfence();                       // release negpart (device scope)
        u32 prev = atomicAdd(ticket, 1u);      // device-scope atomic
        lastflag = (prev == NBLK - 1);
    }
    __syncthreads();
    if (!lastflag) return;

    // ---- fused finalize (last block only) — identical reduction tree to the
    // old finalize kernel, so the result is bit-exact.
    __threadfence();                           // acquire: invalidate caches
    float sp = 0.f, sn = 0.f;
    #pragma unroll
    for (int i = 0; i < 16; ++i) sp += pospart[i * 256 + tid];
    #pragma unroll
    for (int i = 0; i < 4;  ++i) sn += negpart[i * 256 + tid];
    sp = wave_reduce(sp);
    sn = wave_reduce(sn);
    __shared__ float rp[4], rn[4];
    if (lane == 0) { rp[wave] = sp; rn[wave] = sn; }
    __syncthreads();
    if (tid == 0) {
        float pos = rp[0] + rp[1] + rp[2] + rp[3];
        float neg = rn[0] + rn[1] + rn[2] + rn[3];
        out[0] = pos * (1.0f / (float)N_ROWS)
               + neg * (1.0f / ((float)N_ROWS * (float)N_ROWS));
    }
}

// ---------------- launch ----------------

extern "C" void kernel_launch(void* const* d_in, const int* in_sizes, int n_in,
                              void* d_out, int out_size, void* d_ws, size_t ws_size,
                              hipStream_t stream) {
    const float* img = (const float*)d_in[0];
    const float* txt = (const float*)d_in[1];
    float* out = (float*)d_out;

    u8* imgn = (u8*)d_ws;                                     // 2 MiB (fp4)
    u8* txtn = imgn + (size_t)N_ROWS * ROWB;                  // 2 MiB
    float* pospart = (float*)(txtn + (size_t)N_ROWS * ROWB);  // 16 KiB (4096)
    float* negpart = pospart + 4096;                          // 4 KiB (1024)
    u32* ticket = (u32*)(negpart + 1024);                     // 4 B

    rowprep<<<N_ROWS / 2, 256, 0, stream>>>(img, txt, imgn, txtn, pospart, ticket);
    negloss<<<dim3(N_ROWS / BN, N_ROWS / BM), 256, 0, stream>>>(
        imgn, txtn, pospart, negpart, ticket, out);
}

// Round 4
// 89.688 us; speedup vs baseline: 1.4597x; 1.2006x over previous
//
#include <hip/hip_runtime.h>
#include <hip/hip_bf16.h>

typedef unsigned char  u8;
typedef unsigned int   u32;
typedef __attribute__((ext_vector_type(4))) int   int4v;
typedef __attribute__((ext_vector_type(8))) int   int8v;
typedef __attribute__((ext_vector_type(4))) float float4v;

#define N_ROWS 4096
#define DIM    1024
#define MARGIN 0.5f
#define FP4_SCALE 32.0f          // rows scaled to ~N(0,1) before e2m1 quantization
#define INV_SCALE2 (1.0f / (FP4_SCALE * FP4_SCALE))
#define ROWB 512                 // bytes per row in fp4 (1024 elems / 2)

// ---------------- helpers ----------------

__device__ __forceinline__ float wave_reduce(float v) {
    #pragma unroll
    for (int off = 32; off > 0; off >>= 1) v += __shfl_xor(v, off, 64);
    return v;   // butterfly: ALL lanes hold the sum
}

__device__ __forceinline__ void gl_lds16(const void* g, void* l) {
    __builtin_amdgcn_global_load_lds(
        (const __attribute__((address_space(1))) void*)g,
        (__attribute__((address_space(3))) void*)l,
        16, 0, 0);
}

// e2m1 quantization: grid {0,.5,1,1.5,2,3,4,6}, input pre-scaled to ~N(0,1).
__device__ __forceinline__ u32 q4(float v) {
    float a = fabsf(v);
    u32 c = (a >= 0.25f) + (a >= 0.75f) + (a >= 1.25f) + (a >= 1.75f)
          + (a >= 2.5f)  + (a >= 3.5f)  + (a >= 5.0f);
    return c | (v < 0.0f ? 8u : 0u);
}

// ---------------- kernel 1: norms + positive term + fp4 pre-normalized copies ----------------
// TWO waves per row (half-row each). 2048 blocks x 256 thr. Lane: 8 fp32/input
// -> 8 fp4 nibbles = 1 dword store per input.

__global__ __launch_bounds__(256) void rowprep(
        const float* __restrict__ img, const float* __restrict__ txt,
        u8* __restrict__ imgn, u8* __restrict__ txtn,
        float* __restrict__ pospart) {
    const int t = threadIdx.x;
    const int wave = t >> 6, lane = t & 63;
    const int row  = blockIdx.x * 2 + (wave >> 1);
    const int half = wave & 1;

    const float4* ip = (const float4*)img + (size_t)row * 256 + half * 128;
    const float4* tp = (const float4*)txt + (size_t)row * 256 + half * 128;

    float4 iv[2], tv[2];
    #pragma unroll
    for (int k = 0; k < 2; ++k) {
        iv[k] = ip[k * 64 + lane];
        tv[k] = tp[k * 64 + lane];
    }

    float sii = 0.f, si2 = 0.f, st2 = 0.f;
    #pragma unroll
    for (int k = 0; k < 2; ++k) {
        sii += iv[k].x*tv[k].x + iv[k].y*tv[k].y + iv[k].z*tv[k].z + iv[k].w*tv[k].w;
        si2 += iv[k].x*iv[k].x + iv[k].y*iv[k].y + iv[k].z*iv[k].z + iv[k].w*iv[k].w;
        st2 += tv[k].x*tv[k].x + tv[k].y*tv[k].y + tv[k].z*tv[k].z + tv[k].w*tv[k].w;
    }

    sii = wave_reduce(sii);
    si2 = wave_reduce(si2);
    st2 = wave_reduce(st2);

    __shared__ float red[4][3];
    if (lane == 0) { red[wave][0] = sii; red[wave][1] = si2; red[wave][2] = st2; }
    __syncthreads();
    const int pw = wave ^ 1;
    sii += red[pw][0];
    si2 += red[pw][1];
    st2 += red[pw][2];

    float ni = fmaxf(sqrtf(si2), 1e-8f);
    float nt = fmaxf(sqrtf(st2), 1e-8f);
    float ii = 1.0f / ni, it = 1.0f / nt;
    float si = FP4_SCALE * ii, st = FP4_SCALE * it;

    // pack 8 fp4 codes per input into one dword (elem j -> nibble j)
    u32 pa = 0, pb = 0;
    #pragma unroll
    for (int k = 0; k < 2; ++k) {
        pa |= q4(iv[k].x * si) << (k*16 + 0);  pa |= q4(iv[k].y * si) << (k*16 + 4);
        pa |= q4(iv[k].z * si) << (k*16 + 8);  pa |= q4(iv[k].w * si) << (k*16 + 12);
        pb |= q4(tv[k].x * st) << (k*16 + 0);  pb |= q4(tv[k].y * st) << (k*16 + 4);
        pb |= q4(tv[k].z * st) << (k*16 + 8);  pb |= q4(tv[k].w * st) << (k*16 + 12);
    }
    // row = 512 B = 128 dwords; half-row = 64 dwords
    ((u32*)imgn)[(size_t)row * 128 + half * 64 + lane] = pa;
    ((u32*)txtn)[(size_t)row * 128 + half * 64 + lane] = pb;

    if (half == 0 && lane == 0) {
        float d = 1.0f - sii * ii * it;
        pospart[row] = d * d;
    }
}

// ---------------- kernel 2: pairwise cosine GEMM (MX-fp4 K=128) + fused hinge ----------------
// A (imgn), B (txtn): row-major [4096][512 B] fp4 e2m1, pre-normalized * 32.
// 128x128 block tile, 4 waves (2x2), 64x64 wave tiles of 4x4 16x16x128
// scaled-MFMA (fmt=4: fp4, scales=1.0). BK=256 elems = 128 B rows; XOR-16B-
// chunk swizzle; fragment = ONE b128 per matrix per k-step.
//
// ROUND-4 CHANGE vs the proven r0 structure (everything else identical):
// DOUBLE-BUFFERED at BK=256 (2 x 32 KiB = 64 KiB LDS), prefetch distance 1,
// ONE barrier per iter instead of two. The 8 staging loads for iter+1 fly
// under the 32-MFMA compute phase (~400-800 cy >> L2 latency ~200-400 cy),
// so the barrier's vmcnt(0) drain is ~free. LDS caps residency at 2 blk/CU;
// explicit prefetch replaces the lost TLP (r2 proved TLP without staging is
// worthless here: 59.5 us at MfmaUtil 5%).
// NO fence/ticket fusion: r3 proved 1024 per-block device fences cost ~+18 us
// (L2 writeback interference with the L2-resident operand stream).

#define BM 128
#define BN 128

__global__ __launch_bounds__(256) void negloss(
        const u8* __restrict__ A, const u8* __restrict__ B,
        float* __restrict__ negpart) {
    __shared__ __align__(16) u8 sA[2][BM * 128];   // 2 x 16 KiB
    __shared__ __align__(16) u8 sB[2][BN * 128];   // 2 x 16 KiB

    const int tid = threadIdx.x;
    const int wave = tid >> 6, lane = tid & 63;
    const int wr = wave >> 1, wc = wave & 1;
    const int rA0 = blockIdx.y * BM;
    const int rB0 = blockIdx.x * BN;

    const int mrow = lane & 15;     // fragment row within 16
    const int kg = lane >> 4;       // k-group: 32 K-elems = 16 B per k-step

    // staging: load r (0..3): row = r*32 + wave*8 + (lane>>3),
    // swizzled chunk lc = (lane&7)^(lane>>3) (r/iter-invariant),
    // LDS dest (wave-uniform) = r*4096 + wave*1024.
    const int lc = (lane & 7) ^ (lane >> 3);
    const u8* gA0 = A + (size_t)(rA0 + wave * 8 + (lane >> 3)) * ROWB + lc * 16;
    const u8* gB0 = B + (size_t)(rB0 + wave * 8 + (lane >> 3)) * ROWB + lc * 16;

    float4v acc[4][4] = {};

    // prologue: stage iter 0 into buffer 0
    #pragma unroll
    for (int r = 0; r < 4; ++r) {
        int uoff = r * 4096 + wave * 1024;
        gl_lds16(gA0 + (size_t)r * (32 * ROWB), (char*)sA[0] + uoff);
        gl_lds16(gB0 + (size_t)r * (32 * ROWB), (char*)sB[0] + uoff);
    }
    __syncthreads();                // vmcnt(0) drain -> buf0 visible

    #pragma unroll
    for (int it = 0; it < 4; ++it) {            // BK = 256 elems = 128 B
        const int b = it & 1;

        // prefetch iter+1 into the other buffer — in flight under compute
        if (it < 3) {
            #pragma unroll
            for (int r = 0; r < 4; ++r) {
                int uoff = r * 4096 + wave * 1024;
                gl_lds16(gA0 + (size_t)r * (32 * ROWB) + (it + 1) * 128,
                         (char*)sA[b ^ 1] + uoff);
                gl_lds16(gB0 + (size_t)r * (32 * ROWB) + (it + 1) * 128,
                         (char*)sB[b ^ 1] + uoff);
            }
        }

        // compute current buffer: 2 K=128 steps x 16 MFMA
        #pragma unroll
        for (int s = 0; s < 2; ++s) {
            const int ch = s * 4 + kg;          // logical 16B chunk for this k-step
            int8v af[4], bf[4];
            #pragma unroll
            for (int i = 0; i < 4; ++i) {
                int ra = wr * 64 + i * 16 + mrow;
                int4v a = *(const int4v*)(sA[b] + ra * 128 + (ch ^ (ra & 7)) * 16);
                int rb = wc * 64 + i * 16 + mrow;
                int4v b2 = *(const int4v*)(sB[b] + rb * 128 + (ch ^ (rb & 7)) * 16);
                af[i] = int8v{a[0], a[1], a[2], a[3], 0, 0, 0, 0};
                bf[i] = int8v{b2[0], b2[1], b2[2], b2[3], 0, 0, 0, 0};
            }
            #pragma unroll
            for (int i = 0; i < 4; ++i)
                #pragma unroll
                for (int j = 0; j < 4; ++j)
                    acc[i][j] = __builtin_amdgcn_mfma_scale_f32_16x16x128_f8f6f4(
                        af[i], bf[j], acc[i][j],
                        4 /*A fmt: fp4 e2m1*/, 4 /*B fmt: fp4 e2m1*/,
                        0, 0x7F7F7F7F /*scale A = 1.0*/,
                        0, 0x7F7F7F7F /*scale B = 1.0*/);
        }

        // one barrier per iter: drains prefetch (vmcnt) + LDS reads (lgkm);
        // publishes buf^1 and protects buf from early overwrite next iter.
        __syncthreads();
    }

    // epilogue: C/D layout (16x16 shapes): col = lane&15, row = (lane>>4)*4 + reg
    float local = 0.0f;
    const int crow = (lane >> 4) * 4;
    const int ccol = lane & 15;
    #pragma unroll
    for (int i = 0; i < 4; ++i) {
        int gi_base = rA0 + wr * 64 + i * 16 + crow;
        #pragma unroll
        for (int j = 0; j < 4; ++j) {
            int gj = rB0 + wc * 64 + j * 16 + ccol;
            #pragma unroll
            for (int r = 0; r < 4; ++r) {
                float sim = acc[i][j][r] * INV_SCALE2;
                float h = fmaxf(sim - MARGIN, 0.0f);
                if (gi_base + r == gj) h = 0.0f;   // diagonal zeroed
                local += h * h;
            }
        }
    }

    local = wave_reduce(local);
    __shared__ float part[4];
    if (lane == 0) part[wave] = local;
    __syncthreads();
    if (tid == 0)
        negpart[blockIdx.y * gridDim.x + blockIdx.x] = part[0] + part[1] + part[2] + part[3];
}

// ---------------- kernel 3: final reduction ----------------
// pospart: 4096 entries (one per row). negpart: 1024 entries (one per block).

__global__ __launch_bounds__(256) void finalize(
        const float* __restrict__ pospart, const float* __restrict__ negpart,
        float* __restrict__ out) {
    const int t = threadIdx.x;
    const int wave = t >> 6, lane = t & 63;
    float sp = 0.f, sn = 0.f;
    #pragma unroll
    for (int i = 0; i < 16; ++i) sp += pospart[i * 256 + t];
    #pragma unroll
    for (int i = 0; i < 4; ++i)  sn += negpart[i * 256 + t];
    sp = wave_reduce(sp);
    sn = wave_reduce(sn);
    __shared__ float rp[4], rn[4];
    if (lane == 0) { rp[wave] = sp; rn[wave] = sn; }
    __syncthreads();
    if (t == 0) {
        float pos = rp[0] + rp[1] + rp[2] + rp[3];
        float neg = rn[0] + rn[1] + rn[2] + rn[3];
        out[0] = pos * (1.0f / (float)N_ROWS)
               + neg * (1.0f / ((float)N_ROWS * (float)N_ROWS));
    }
}

// ---------------- launch ----------------

extern "C" void kernel_launch(void* const* d_in, const int* in_sizes, int n_in,
                              void* d_out, int out_size, void* d_ws, size_t ws_size,
                              hipStream_t stream) {
    const float* img = (const float*)d_in[0];
    const float* txt = (const float*)d_in[1];
    float* out = (float*)d_out;

    u8* imgn = (u8*)d_ws;                                     // 2 MiB (fp4)
    u8* txtn = imgn + (size_t)N_ROWS * ROWB;                  // 2 MiB
    float* pospart = (float*)(txtn + (size_t)N_ROWS * ROWB);  // 16 KiB (4096)
    float* negpart = pospart + 4096;                          // 4 KiB (1024)

    rowprep<<<N_ROWS / 2, 256, 0, stream>>>(img, txt, imgn, txtn, pospart);
    negloss<<<dim3(N_ROWS / BN, N_ROWS / BM), 256, 0, stream>>>(imgn, txtn, negpart);
    finalize<<<1, 256, 0, stream>>>(pospart, negpart, out);
}

// Round 5
// 88.195 us; speedup vs baseline: 1.4844x; 1.0169x over previous
//
#include <hip/hip_runtime.h>
#include <hip/hip_bf16.h>

typedef unsigned char  u8;
typedef unsigned int   u32;
typedef __attribute__((ext_vector_type(4))) int   int4v;
typedef __attribute__((ext_vector_type(8))) int   int8v;
typedef __attribute__((ext_vector_type(4))) float float4v;

#define N_ROWS 4096
#define DIM    1024
#define MARGIN 0.5f
#define FP4_SCALE 32.0f          // rows scaled to ~N(0,1) before e2m1 quantization
#define INV_SCALE2 (1.0f / (FP4_SCALE * FP4_SCALE))
#define ROWB 512                 // bytes per row in fp4 (1024 elems / 2)

// ---------------- helpers ----------------

__device__ __forceinline__ float wave_reduce(float v) {
    #pragma unroll
    for (int off = 32; off > 0; off >>= 1) v += __shfl_xor(v, off, 64);
    return v;   // butterfly: ALL lanes hold the sum
}

__device__ __forceinline__ void gl_lds16(const void* g, void* l) {
    __builtin_amdgcn_global_load_lds(
        (const __attribute__((address_space(1))) void*)g,
        (__attribute__((address_space(3))) void*)l,
        16, 0, 0);
}

// e2m1 quantization: grid {0,.5,1,1.5,2,3,4,6}, input pre-scaled to ~N(0,1).
__device__ __forceinline__ u32 q4(float v) {
    float a = fabsf(v);
    u32 c = (a >= 0.25f) + (a >= 0.75f) + (a >= 1.25f) + (a >= 1.75f)
          + (a >= 2.5f)  + (a >= 3.5f)  + (a >= 5.0f);
    return c | (v < 0.0f ? 8u : 0u);
}

// ---------------- kernel 1: norms + positive term + fp4 pre-normalized copies ----------------
// TWO waves per row (half-row each). 2048 blocks x 256 thr. Lane: 8 fp32/input
// -> 8 fp4 nibbles = 1 dword store per input.

__global__ __launch_bounds__(256) void rowprep(
        const float* __restrict__ img, const float* __restrict__ txt,
        u8* __restrict__ imgn, u8* __restrict__ txtn,
        float* __restrict__ pospart) {
    const int t = threadIdx.x;
    const int wave = t >> 6, lane = t & 63;
    const int row  = blockIdx.x * 2 + (wave >> 1);
    const int half = wave & 1;

    const float4* ip = (const float4*)img + (size_t)row * 256 + half * 128;
    const float4* tp = (const float4*)txt + (size_t)row * 256 + half * 128;

    float4 iv[2], tv[2];
    #pragma unroll
    for (int k = 0; k < 2; ++k) {
        iv[k] = ip[k * 64 + lane];
        tv[k] = tp[k * 64 + lane];
    }

    float sii = 0.f, si2 = 0.f, st2 = 0.f;
    #pragma unroll
    for (int k = 0; k < 2; ++k) {
        sii += iv[k].x*tv[k].x + iv[k].y*tv[k].y + iv[k].z*tv[k].z + iv[k].w*tv[k].w;
        si2 += iv[k].x*iv[k].x + iv[k].y*iv[k].y + iv[k].z*iv[k].z + iv[k].w*iv[k].w;
        st2 += tv[k].x*tv[k].x + tv[k].y*tv[k].y + tv[k].z*tv[k].z + tv[k].w*tv[k].w;
    }

    sii = wave_reduce(sii);
    si2 = wave_reduce(si2);
    st2 = wave_reduce(st2);

    __shared__ float red[4][3];
    if (lane == 0) { red[wave][0] = sii; red[wave][1] = si2; red[wave][2] = st2; }
    __syncthreads();
    const int pw = wave ^ 1;
    sii += red[pw][0];
    si2 += red[pw][1];
    st2 += red[pw][2];

    float ni = fmaxf(sqrtf(si2), 1e-8f);
    float nt = fmaxf(sqrtf(st2), 1e-8f);
    float ii = 1.0f / ni, it = 1.0f / nt;
    float si = FP4_SCALE * ii, st = FP4_SCALE * it;

    // pack 8 fp4 codes per input into one dword (elem j -> nibble j)
    u32 pa = 0, pb = 0;
    #pragma unroll
    for (int k = 0; k < 2; ++k) {
        pa |= q4(iv[k].x * si) << (k*16 + 0);  pa |= q4(iv[k].y * si) << (k*16 + 4);
        pa |= q4(iv[k].z * si) << (k*16 + 8);  pa |= q4(iv[k].w * si) << (k*16 + 12);
        pb |= q4(tv[k].x * st) << (k*16 + 0);  pb |= q4(tv[k].y * st) << (k*16 + 4);
        pb |= q4(tv[k].z * st) << (k*16 + 8);  pb |= q4(tv[k].w * st) << (k*16 + 12);
    }
    // row = 512 B = 128 dwords; half-row = 64 dwords
    ((u32*)imgn)[(size_t)row * 128 + half * 64 + lane] = pa;
    ((u32*)txtn)[(size_t)row * 128 + half * 64 + lane] = pb;

    if (half == 0 && lane == 0) {
        float d = 1.0f - sii * ii * it;
        pospart[row] = d * d;
    }
}

// ---------------- kernel 2: pairwise cosine GEMM (MX-fp4 K=128) + fused hinge ----------------
// A (imgn), B (txtn): row-major [4096][512 B] fp4 e2m1, pre-normalized * 32.
//
// ROUND-5 CHANGE: 256x256 block tile (parameter-scale of the r4-verified
// dbuf template; same sync structure, absmax 0.0 proven).
//   Rationale: r0/r1/r4 schedules at 128^2 were a 3-way tie -> schedule is
//   not the lever. 128^2 = 1024 blocks = 2-4 block GENERATIONS per CU, each
//   paying naked prologue (cold stage) + epilogue (~2-3 us) on a ~19 us
//   kernel, plus 2x redundant L2 operand traffic. 256^2 -> 256 blocks =
//   EXACTLY 1 block/CU, one generation, no tail; L2 traffic halves.
//   At 1 block/CU there is no sibling block to hide staging, so the dbuf
//   (one barrier/iter, prefetch under 64 MFMAs ~2800cy >> L2 latency) is
//   what keeps the staging off the critical path.
// 512 thr, 8 waves (2x4), wave tile 128x64 = 8x4 16x16x128 scaled-MFMA
// (fmt=4: fp4, scales=1.0); acc = 128 VGPR. BK=256 elems = 128 B rows;
// XOR-16B-chunk swizzle unchanged (all staged-row offsets = 0 mod 8).
// LDS: 2 x (32+32) KiB = 128 KiB <= 160.

#define BM 256
#define BN 256

__global__ __launch_bounds__(512) void negloss(
        const u8* __restrict__ A, const u8* __restrict__ B,
        float* __restrict__ negpart) {
    __shared__ __align__(16) u8 sA[2][BM * 128];   // 2 x 32 KiB
    __shared__ __align__(16) u8 sB[2][BN * 128];   // 2 x 32 KiB

    const int tid = threadIdx.x;
    const int wave = tid >> 6, lane = tid & 63;
    const int wr = wave >> 2, wc = wave & 3;       // 2 x 4 wave grid
    const int rA0 = blockIdx.y * BM;
    const int rB0 = blockIdx.x * BN;

    const int mrow = lane & 15;     // fragment row within 16
    const int kg = lane >> 4;       // k-group: 32 K-elems = 16 B per k-step

    // staging: r (0..3): row = r*64 + wave*8 + (lane>>3)  [row%8 == lane>>3],
    // swizzled chunk lc = (lane&7)^(lane>>3), LDS dest = r*8192 + wave*1024.
    // Per iter each wave stages 4 KiB of A + 4 KiB of B (8 x gl_lds16).
    const int lc = (lane & 7) ^ (lane >> 3);
    const u8* gA0 = A + (size_t)(rA0 + wave * 8 + (lane >> 3)) * ROWB + lc * 16;
    const u8* gB0 = B + (size_t)(rB0 + wave * 8 + (lane >> 3)) * ROWB + lc * 16;

    float4v acc[8][4] = {};

    // prologue: stage iter 0 into buffer 0
    #pragma unroll
    for (int r = 0; r < 4; ++r) {
        int uoff = r * 8192 + wave * 1024;
        gl_lds16(gA0 + (size_t)r * (64 * ROWB), (char*)sA[0] + uoff);
        gl_lds16(gB0 + (size_t)r * (64 * ROWB), (char*)sB[0] + uoff);
    }
    __syncthreads();                // vmcnt(0) drain -> buf0 visible

    #pragma unroll
    for (int it = 0; it < 4; ++it) {            // BK = 256 elems = 128 B
        const int b = it & 1;

        // prefetch iter+1 into the other buffer — in flight under compute
        if (it < 3) {
            #pragma unroll
            for (int r = 0; r < 4; ++r) {
                int uoff = r * 8192 + wave * 1024;
                gl_lds16(gA0 + (size_t)r * (64 * ROWB) + (it + 1) * 128,
                         (char*)sA[b ^ 1] + uoff);
                gl_lds16(gB0 + (size_t)r * (64 * ROWB) + (it + 1) * 128,
                         (char*)sB[b ^ 1] + uoff);
            }
        }

        // compute current buffer: 2 K=128 steps x 32 MFMA
        #pragma unroll
        for (int s = 0; s < 2; ++s) {
            const int ch = s * 4 + kg;          // logical 16B chunk for this k-step
            int8v af[8], bf[4];
            #pragma unroll
            for (int i = 0; i < 8; ++i) {
                int ra = wr * 128 + i * 16 + mrow;
                int4v a = *(const int4v*)(sA[b] + ra * 128 + (ch ^ (ra & 7)) * 16);
                af[i] = int8v{a[0], a[1], a[2], a[3], 0, 0, 0, 0};
            }
            #pragma unroll
            for (int j = 0; j < 4; ++j) {
                int rb = wc * 64 + j * 16 + mrow;
                int4v b2 = *(const int4v*)(sB[b] + rb * 128 + (ch ^ (rb & 7)) * 16);
                bf[j] = int8v{b2[0], b2[1], b2[2], b2[3], 0, 0, 0, 0};
            }
            #pragma unroll
            for (int i = 0; i < 8; ++i)
                #pragma unroll
                for (int j = 0; j < 4; ++j)
                    acc[i][j] = __builtin_amdgcn_mfma_scale_f32_16x16x128_f8f6f4(
                        af[i], bf[j], acc[i][j],
                        4 /*A fmt: fp4 e2m1*/, 4 /*B fmt: fp4 e2m1*/,
                        0, 0x7F7F7F7F /*scale A = 1.0*/,
                        0, 0x7F7F7F7F /*scale B = 1.0*/);
        }

        // one barrier per iter: drains prefetch (vmcnt) + LDS reads (lgkm);
        // publishes buf^1 and protects buf from early overwrite next iter.
        __syncthreads();
    }

    // epilogue: C/D layout (16x16 shapes): col = lane&15, row = (lane>>4)*4 + reg
    float local = 0.0f;
    const int crow = (lane >> 4) * 4;
    const int ccol = lane & 15;
    #pragma unroll
    for (int i = 0; i < 8; ++i) {
        int gi_base = rA0 + wr * 128 + i * 16 + crow;
        #pragma unroll
        for (int j = 0; j < 4; ++j) {
            int gj = rB0 + wc * 64 + j * 16 + ccol;
            #pragma unroll
            for (int r = 0; r < 4; ++r) {
                float sim = acc[i][j][r] * INV_SCALE2;
                float h = fmaxf(sim - MARGIN, 0.0f);
                if (gi_base + r == gj) h = 0.0f;   // diagonal zeroed
                local += h * h;
            }
        }
    }

    local = wave_reduce(local);
    __shared__ float part[8];
    if (lane == 0) part[wave] = local;
    __syncthreads();
    if (tid == 0) {
        float s = 0.f;
        #pragma unroll
        for (int w = 0; w < 8; ++w) s += part[w];
        negpart[blockIdx.y * gridDim.x + blockIdx.x] = s;
    }
}

// ---------------- kernel 3: final reduction ----------------
// pospart: 4096 entries (one per row). negpart: 256 entries (one per block).

__global__ __launch_bounds__(256) void finalize(
        const float* __restrict__ pospart, const float* __restrict__ negpart,
        float* __restrict__ out) {
    const int t = threadIdx.x;
    const int wave = t >> 6, lane = t & 63;
    float sp = 0.f;
    #pragma unroll
    for (int i = 0; i < 16; ++i) sp += pospart[i * 256 + t];
    float sn = negpart[t];
    sp = wave_reduce(sp);
    sn = wave_reduce(sn);
    __shared__ float rp[4], rn[4];
    if (lane == 0) { rp[wave] = sp; rn[wave] = sn; }
    __syncthreads();
    if (t == 0) {
        float pos = rp[0] + rp[1] + rp[2] + rp[3];
        float neg = rn[0] + rn[1] + rn[2] + rn[3];
        out[0] = pos * (1.0f / (float)N_ROWS)
               + neg * (1.0f / ((float)N_ROWS * (float)N_ROWS));
    }
}

// ---------------- launch ----------------

extern "C" void kernel_launch(void* const* d_in, const int* in_sizes, int n_in,
                              void* d_out, int out_size, void* d_ws, size_t ws_size,
                              hipStream_t stream) {
    const float* img = (const float*)d_in[0];
    const float* txt = (const float*)d_in[1];
    float* out = (float*)d_out;

    u8* imgn = (u8*)d_ws;                                     // 2 MiB (fp4)
    u8* txtn = imgn + (size_t)N_ROWS * ROWB;                  // 2 MiB
    float* pospart = (float*)(txtn + (size_t)N_ROWS * ROWB);  // 16 KiB (4096)
    float* negpart = pospart + 4096;                          // 1 KiB (256)

    rowprep<<<N_ROWS / 2, 256, 0, stream>>>(img, txt, imgn, txtn, pospart);
    negloss<<<dim3(N_ROWS / BN, N_ROWS / BM), 512, 0, stream>>>(imgn, txtn, negpart);
    finalize<<<1, 256, 0, stream>>>(pospart, negpart, out);
}